// Round 25
// baseline (1412.806 us; speedup 1.0000x reference)
//
#include <hip/hip_runtime.h>
#include <float.h>
#include <limits.h>

// N=131072, K=2048, D=64.
// Verified reference scheme R (rounds 5/7/9-23, absmax 0.0):
//   xsq: numpy NPY_SIMD-128 pairwise (8 vec-accs x 4 lanes + SSE3 hadd tree)
//   esq: scalar pairwise-8; dot: any fp32 order (proven);
//   dist=fl(fl(xsq+esq)-2dot); argmin first-index.
// Round 25 = R24 (BM=256, 2 row-tiles/wave -> ds_read per MFMA halved,
// KT=256, 8 phases/pass) with the LDS overflow fixed: R24's 81920-byte
// block hit the exact 2-blocks/CU boundary and rounded DOWN to 1 block/CU
// (occupancy 28%, 583us serial-batch regression). Diet: CAND_CAP 12->8
// (cand_s 12->8 KB) => ~77.3 KB, safely 2 blocks/CU. Overflow P(>8)~0.3%/row
// -> ~0.7 rows/block through the lossless full-scan fallback (~1us/block).
// Algorithm unchanged: folded -2e bf16 MFMA screen, 2-pass margin collect,
// exact R rescore (x from global, float4 same-d-order), lossless fallback.
#define D_DIM 64
#define K_CB  2048
#define BM    256
#define NTHREADS 512
#define NWAVES 8
#define KT    256               // codes per staged tile (32 KB)
#define NT    (K_CB / KT)       // 8 tiles
#define MARGIN 2e-3f
#define CAND_CAP 8

typedef __attribute__((ext_vector_type(4))) float f32x4;
typedef __attribute__((ext_vector_type(8))) short s16x8;

__device__ __forceinline__ short f2bf(float f) {   // RN-even fp32->bf16 bits
  unsigned u = __builtin_bit_cast(unsigned, f);
  u += 0x7fffu + ((u >> 16) & 1u);
  return (short)(unsigned short)(u >> 16);
}

__device__ __forceinline__ void gload_lds16(const void* g, void* l) {
  __builtin_amdgcn_global_load_lds(
      (const __attribute__((address_space(1))) unsigned int*)g,
      (__attribute__((address_space(3))) unsigned int*)l, 16, 0, 0);
}

// prep: esq[k] (scalar-8 numpy order, verified) + bf16(-2*e) PRE-SWIZZLED:
//   cbh[k*64 + (d ^ ((k&7)<<3))] = bf16(-2*cb[k][d])
__global__ void __launch_bounds__(256) prep_kernel(const float* __restrict__ cb,
                                                   float* __restrict__ esq,
                                                   unsigned short* __restrict__ cbh) {
#pragma clang fp contract(off)
  int k = blockIdx.x * 256 + threadIdx.x;
  if (k >= K_CB) return;
  const float* row = cb + (size_t)k * D_DIM;
  float r[8];
#pragma unroll
  for (int j = 0; j < 8; ++j) { float v = row[j]; r[j] = v * v; }
#pragma unroll
  for (int i = 1; i < 8; ++i)
#pragma unroll
    for (int j = 0; j < 8; ++j) { float v = row[8 * i + j]; r[j] += v * v; }
  esq[k] = ((r[0] + r[1]) + (r[2] + r[3])) + ((r[4] + r[5]) + (r[6] + r[7]));
  unsigned short* o = cbh + (size_t)k * D_DIM;
  const int sw = (k & 7) << 3;
#pragma unroll
  for (int d = 0; d < D_DIM; ++d)
    o[d ^ sw] = (unsigned short)f2bf(-2.0f * row[d]);
}

__global__ void __launch_bounds__(NTHREADS)
vq_mfma_kernel(const float* __restrict__ x,
               const float* __restrict__ cb,
               const float* __restrict__ esq,
               const unsigned short* __restrict__ cbh,
               float* __restrict__ out) {
#pragma clang fp contract(off)
  // 64 KB region: prologue = fp32 x tile (256 rows); steady = bbuf[2]x32KB.
  __shared__ __align__(16) char smem[65536];
  __shared__ int   cand_s[BM * CAND_CAP];          // 8 KB; fb overlaid at end
  __shared__ float xsq_s[BM];                      // 1 KB
  __shared__ int   cnt_s[BM];                      // 1 KB
  __shared__ int   bestk_s[BM];                    // 1 KB
  __shared__ unsigned short ovf_rows[BM];          // 0.5 KB
  __shared__ int   ovf_cnt;

  const int tid  = threadIdx.x;
  const int lane = tid & 63;
  const int wave = tid >> 6;
  const int row0 = blockIdx.x * BM;

  float4* xs4 = (float4*)smem;                     // prologue view

  // ---- stage x tile (coalesced float4), swizzle float4-col ^= (row>>2)&7 ----
  const float4* xg = (const float4*)(x + (size_t)row0 * D_DIM);
#pragma unroll
  for (int i = 0; i < 8; ++i) {
    int f = tid + i * NTHREADS;                    // 4096 float4
    int row = f >> 4, c4 = f & 15;
    xs4[row * 16 + (c4 ^ ((row >> 2) & 7))] = xg[f];
  }
  if (tid == 0) ovf_cnt = 0;
  if (tid < BM) cnt_s[tid] = 0;
  __syncthreads();

  // ---- xsq per row: numpy NPY_SIMD-128 pairwise emulation (verified R5) ----
  if (tid < BM) {
    const int swz = 4 * ((tid >> 2) & 7);
    const float* xr = (const float*)xs4 + tid * 64;
    float s[4];
#pragma unroll
    for (int l = 0; l < 4; ++l) {
      float rj[8];
#pragma unroll
      for (int j = 0; j < 8; ++j) {
        float a = xr[(4 * j + l) ^ swz];
        float b = xr[(32 + 4 * j + l) ^ swz];
        float ta = a * a;
        float tb = b * b;
        rj[j] = ta + tb;
      }
      s[l] = ((rj[0] + rj[1]) + (rj[2] + rj[3])) +
             ((rj[4] + rj[5]) + (rj[6] + rj[7]));
    }
    xsq_s[tid] = (s[0] + s[1]) + (s[2] + s[3]);
  }

  // ---- A fragments: wave owns rows wave*32..wave*32+31 (2 row-tiles).
  //   16x16x32 maps (m89-verified): A: lane row=lane&15, k=(lane>>4)*8+j;
  //   B: col=lane&15, same k; C: col=lane&15, row=(lane>>4)*4+r.
  s16x8 a0[2], a1[2];
  {
    const int arow = lane & 15;
    const int kgA = (lane >> 4) * 8;
#pragma unroll
    for (int rt = 0; rt < 2; ++rt) {
      int row = wave * 32 + rt * 16 + arow;
      int sw = (row >> 2) & 7;
      {
        int q0 = kgA >> 2;
        float4 f0 = xs4[row * 16 + (q0 ^ sw)];
        float4 f1 = xs4[row * 16 + ((q0 + 1) ^ sw)];
        a0[rt][0] = f2bf(f0.x); a0[rt][1] = f2bf(f0.y);
        a0[rt][2] = f2bf(f0.z); a0[rt][3] = f2bf(f0.w);
        a0[rt][4] = f2bf(f1.x); a0[rt][5] = f2bf(f1.y);
        a0[rt][6] = f2bf(f1.z); a0[rt][7] = f2bf(f1.w);
      }
      {
        int q0 = (32 + kgA) >> 2;
        float4 f0 = xs4[row * 16 + (q0 ^ sw)];
        float4 f1 = xs4[row * 16 + ((q0 + 1) ^ sw)];
        a1[rt][0] = f2bf(f0.x); a1[rt][1] = f2bf(f0.y);
        a1[rt][2] = f2bf(f0.z); a1[rt][3] = f2bf(f0.w);
        a1[rt][4] = f2bf(f1.x); a1[rt][5] = f2bf(f1.y);
        a1[rt][6] = f2bf(f1.z); a1[rt][7] = f2bf(f1.w);
      }
    }
  }
  __syncthreads();   // x tile dead; smem becomes bbuf[2][32KB]

  const int ccol = lane & 15;
  const int kg   = (lane >> 4) * 8;
  const int swb  = (ccol & 7) << 3;                // lane-constant
  const int rbase = wave * 32 + (lane >> 4) * 4;   // + rt*16 + r

  // stage tile t (32 KB) into buffer b: 512 threads x 4 x 16B
  auto STAGE = [&](int t, int b) {
    const char* s0 = (const char*)cbh + (size_t)t * 32768 + wave * 4096 + lane * 16;
    char* d0 = smem + b * 32768 + wave * 4096;
    gload_lds16(s0, d0);
    gload_lds16(s0 + 1024, d0 + 1024);
    gload_lds16(s0 + 2048, d0 + 2048);
    gload_lds16(s0 + 3072, d0 + 3072);
  };

  // ================= pass 1: per-row screen min =================
  float minv[2][4];
#pragma unroll
  for (int rt = 0; rt < 2; ++rt)
#pragma unroll
    for (int r = 0; r < 4; ++r) minv[rt][r] = FLT_MAX;

  STAGE(0, 0);
  __syncthreads();
  for (int t = 0; t < NT; ++t) {
    if (t + 1 < NT) STAGE(t + 1, (t + 1) & 1);
    else            STAGE(0, 0);                   // pass-2's first tile
    const unsigned short* B = (const unsigned short*)(smem + (t & 1) * 32768);
#pragma unroll
    for (int st = 0; st < 16; ++st) {
      const unsigned short* bp = B + (st * 16 + ccol) * 64;
      s16x8 b0 = *(const s16x8*)(bp + (kg ^ swb));
      s16x8 b1 = *(const s16x8*)(bp + ((32 + kg) ^ swb));
#pragma unroll
      for (int rt = 0; rt < 2; ++rt) {
        f32x4 acc = {0.f, 0.f, 0.f, 0.f};
        acc = __builtin_amdgcn_mfma_f32_16x16x32_bf16(a0[rt], b0, acc, 0, 0, 0);
        acc = __builtin_amdgcn_mfma_f32_16x16x32_bf16(a1[rt], b1, acc, 0, 0, 0);
#pragma unroll
        for (int r = 0; r < 4; ++r) minv[rt][r] = fminf(minv[rt][r], acc[r]);
      }
    }
    __syncthreads();   // final iteration's barrier also drains STAGE(0,0)
  }

  // per-row min across the 16 covering lanes -> thr in registers
  float thr[2][4];
#pragma unroll
  for (int rt = 0; rt < 2; ++rt)
#pragma unroll
    for (int r = 0; r < 4; ++r) {
      float v = minv[rt][r];
      v = fminf(v, __shfl_xor(v, 1));
      v = fminf(v, __shfl_xor(v, 2));
      v = fminf(v, __shfl_xor(v, 4));
      v = fminf(v, __shfl_xor(v, 8));
      thr[rt][r] = v + MARGIN;
    }

  // ====== pass 2: recompute (bit-identical), collect candidates ======
  for (int t = 0; t < NT; ++t) {
    if (t + 1 < NT) STAGE(t + 1, (t + 1) & 1);
    const unsigned short* B = (const unsigned short*)(smem + (t & 1) * 32768);
#pragma unroll
    for (int st = 0; st < 16; ++st) {
      const unsigned short* bp = B + (st * 16 + ccol) * 64;
      s16x8 b0 = *(const s16x8*)(bp + (kg ^ swb));
      s16x8 b1 = *(const s16x8*)(bp + ((32 + kg) ^ swb));
#pragma unroll
      for (int rt = 0; rt < 2; ++rt) {
        f32x4 acc = {0.f, 0.f, 0.f, 0.f};
        acc = __builtin_amdgcn_mfma_f32_16x16x32_bf16(a0[rt], b0, acc, 0, 0, 0);
        acc = __builtin_amdgcn_mfma_f32_16x16x32_bf16(a1[rt], b1, acc, 0, 0, 0);
#pragma unroll
        for (int r = 0; r < 4; ++r) {
          if (acc[r] <= thr[rt][r]) {
            int row = rbase + rt * 16 + r;
            int pos = atomicAdd(&cnt_s[row], 1);
            if (pos < CAND_CAP) cand_s[row * CAND_CAP + pos] = t * KT + st * 16 + ccol;
          }
        }
      }
    }
    __syncthreads();
  }

  // ====== exact rescore (R-scheme), lex-(dist,k); 2 threads per row.
  //        x from GLOBAL; float4 loads, IDENTICAL d-order (bit-exact). ======
  {
    const int row = tid >> 1, slot = tid & 1;
    const int cnt = cnt_s[row];
    if (cnt <= CAND_CAP) {
      const float4* xr4 = (const float4*)(x + (size_t)(row0 + row) * D_DIM);
      const float xq = xsq_s[row];
      float bv = FLT_MAX; int bk = INT_MAX;
      for (int i = slot; i < cnt; i += 2) {
        int k = cand_s[row * CAND_CAP + i];
        const float4* er4 = (const float4*)(cb + (size_t)k * D_DIM);
        float a = 0.f;
#pragma unroll
        for (int q = 0; q < 16; ++q) {
          float4 xv = xr4[q], ev = er4[q];
          a = fmaf(xv.x, ev.x, a);
          a = fmaf(xv.y, ev.y, a);
          a = fmaf(xv.z, ev.z, a);
          a = fmaf(xv.w, ev.w, a);
        }
        float dist = (xq + esq[k]) - 2.0f * a;
        if (dist < bv || (dist == bv && k < bk)) { bv = dist; bk = k; }
      }
      {
        float ov = __shfl_xor(bv, 1); int ok = __shfl_xor(bk, 1);
        if (ov < bv || (ov == bv && ok < bk)) { bv = ov; bk = ok; }
      }
      if (slot == 0) bestk_s[row] = bk;
    }
  }
  if (tid < BM && cnt_s[tid] > CAND_CAP) {
    int p = atomicAdd(&ovf_cnt, 1);
    ovf_rows[p] = (unsigned short)tid;
  }
  __syncthreads();

  // ====== lossless overflow fallback: block-cooperative full scan ======
  {
    float* fb_v = (float*)cand_s;                  // cand dead now
    int*   fb_k = (int*)cand_s + 8;
    const int novf = ovf_cnt;
    for (int i = 0; i < novf; ++i) {
      const int row = ovf_rows[i];
      const float4* xr4 = (const float4*)(x + (size_t)(row0 + row) * D_DIM);
      const float xq = xsq_s[row];
      float bv = FLT_MAX; int bk = INT_MAX;
      for (int k = tid; k < K_CB; k += NTHREADS) {
        const float4* er4 = (const float4*)(cb + (size_t)k * D_DIM);
        float a = 0.f;
#pragma unroll
        for (int q = 0; q < 16; ++q) {
          float4 xv = xr4[q], ev = er4[q];
          a = fmaf(xv.x, ev.x, a);
          a = fmaf(xv.y, ev.y, a);
          a = fmaf(xv.z, ev.z, a);
          a = fmaf(xv.w, ev.w, a);
        }
        float dist = (xq + esq[k]) - 2.0f * a;
        if (dist < bv || (dist == bv && k < bk)) { bv = dist; bk = k; }
      }
#pragma unroll
      for (int m = 1; m <= 32; m <<= 1) {
        float ov = __shfl_xor(bv, m); int ok = __shfl_xor(bk, m);
        if (ov < bv || (ov == bv && ok < bk)) { bv = ov; bk = ok; }
      }
      if (lane == 0) { fb_v[wave] = bv; fb_k[wave] = bk; }
      __syncthreads();
      if (tid == 0) {
        float BV = fb_v[0]; int BK = fb_k[0];
#pragma unroll
        for (int w = 1; w < NWAVES; ++w)
          if (fb_v[w] < BV || (fb_v[w] == BV && fb_k[w] < BK)) { BV = fb_v[w]; BK = fb_k[w]; }
        bestk_s[row] = BK;
      }
      __syncthreads();
    }
  }
  __syncthreads();

  // ---- gather: out[row] = codebook[bestk[row]], coalesced float4 ----
  const float4* cb4 = (const float4*)cb;
  float4* out4 = (float4*)out + (size_t)row0 * 16;
#pragma unroll
  for (int i = 0; i < 8; ++i) {
    int f = tid + i * NTHREADS;
    int row = f >> 4, c4 = f & 15;
    out4[f] = cb4[(size_t)bestk_s[row] * 16 + c4];
  }
}

extern "C" void kernel_launch(void* const* d_in, const int* in_sizes, int n_in,
                              void* d_out, int out_size, void* d_ws, size_t ws_size,
                              hipStream_t stream) {
  const float* x  = (const float*)d_in[0];   // [N, 64] fp32
  const float* cb = (const float*)d_in[1];   // [2048, 64] fp32
  float* out = (float*)d_out;                // [N, 64] fp32
  float* esq = (float*)d_ws;                 // [2048] fp32
  unsigned short* cbh = (unsigned short*)d_ws + 4096;  // swizzled bf16(-2e), 256 KB

  const int N = in_sizes[0] / D_DIM;         // 131072

  prep_kernel<<<(K_CB + 255) / 256, 256, 0, stream>>>(cb, esq, cbh);
  vq_mfma_kernel<<<N / BM, NTHREADS, 0, stream>>>(x, cb, esq, cbh, out);
}

// Round 26
// 243.894 us; speedup vs baseline: 5.7927x; 5.7927x over previous
//
#include <hip/hip_runtime.h>
#include <float.h>
#include <limits.h>

// N=131072, K=2048, D=64.
// Verified reference scheme R (rounds 5/7/9-23, absmax 0.0):
//   xsq: numpy NPY_SIMD-128 pairwise (8 vec-accs x 4 lanes + SSE3 hadd tree)
//   esq: scalar pairwise-8; dot: any fp32 order (proven);
//   dist=fl(fl(xsq+esq)-2dot); argmin first-index.
// Round 26 = R23 (verified best, 181.5us) with CAP 24->20 (LDS 80896->78848,
// extra margin under the 2-blocks/CU boundary that R24 proved razor-thin).
// Candidate-count forensics (R23/R24/R25 CAP series): true per-row margin
// count lambda ~5-7 (bf16 screen noise widens the band; small-||x|| rows are
// denser) -> CAP>=20 keeps overflow ~1e-6/row; overflow remains lossless
// via the block-cooperative full exact scan. BM=256 arm abandoned (needs
// CAP>=24 -> LDS >86KB -> 1 block/CU; R24=583us, R25=1442us fallback flood).
// Algorithm: folded -2e bf16 MFMA screen (KT=256, 8 phases/pass, 2-pass),
// exact R rescore (x from global), lossless fallback. 556->181us overall.
#define D_DIM 64
#define K_CB  2048
#define BM    128
#define NTHREADS 512
#define NWAVES 8
#define KT    256               // codes per staged tile (32 KB)
#define NT    (K_CB / KT)       // 8 tiles
#define MARGIN 2e-3f
#define CAND_CAP 20

typedef __attribute__((ext_vector_type(4))) float f32x4;
typedef __attribute__((ext_vector_type(8))) short s16x8;

__device__ __forceinline__ short f2bf(float f) {   // RN-even fp32->bf16 bits
  unsigned u = __builtin_bit_cast(unsigned, f);
  u += 0x7fffu + ((u >> 16) & 1u);
  return (short)(unsigned short)(u >> 16);
}

__device__ __forceinline__ void gload_lds16(const void* g, void* l) {
  __builtin_amdgcn_global_load_lds(
      (const __attribute__((address_space(1))) unsigned int*)g,
      (__attribute__((address_space(3))) unsigned int*)l, 16, 0, 0);
}

// prep: esq[k] (scalar-8 numpy order, verified) + bf16(-2*e) PRE-SWIZZLED:
//   cbh[k*64 + (d ^ ((k&7)<<3))] = bf16(-2*cb[k][d])
__global__ void __launch_bounds__(256) prep_kernel(const float* __restrict__ cb,
                                                   float* __restrict__ esq,
                                                   unsigned short* __restrict__ cbh) {
#pragma clang fp contract(off)
  int k = blockIdx.x * 256 + threadIdx.x;
  if (k >= K_CB) return;
  const float* row = cb + (size_t)k * D_DIM;
  float r[8];
#pragma unroll
  for (int j = 0; j < 8; ++j) { float v = row[j]; r[j] = v * v; }
#pragma unroll
  for (int i = 1; i < 8; ++i)
#pragma unroll
    for (int j = 0; j < 8; ++j) { float v = row[8 * i + j]; r[j] += v * v; }
  esq[k] = ((r[0] + r[1]) + (r[2] + r[3])) + ((r[4] + r[5]) + (r[6] + r[7]));
  unsigned short* o = cbh + (size_t)k * D_DIM;
  const int sw = (k & 7) << 3;
#pragma unroll
  for (int d = 0; d < D_DIM; ++d)
    o[d ^ sw] = (unsigned short)f2bf(-2.0f * row[d]);
}

__global__ void __launch_bounds__(NTHREADS)
vq_mfma_kernel(const float* __restrict__ x,
               const float* __restrict__ cb,
               const float* __restrict__ esq,
               const unsigned short* __restrict__ cbh,
               float* __restrict__ out) {
#pragma clang fp contract(off)
  // 64 KB region: prologue = fp32 x tile (32 KB, first half);
  // steady = bbuf[2] (2 x 32 KB double-buffer).
  __shared__ __align__(16) char smem[65536];
  __shared__ int   cand_s[BM * CAND_CAP];          // 10 KB
  __shared__ float xsq_s[BM];
  __shared__ float rowthr_s[BM];
  __shared__ int   cnt_s[BM];
  __shared__ int   bestk_s[BM];
  __shared__ int   ovf_rows[BM];
  __shared__ int   ovf_cnt;
  __shared__ float fb_v[NWAVES];
  __shared__ int   fb_k[NWAVES];

  const int tid  = threadIdx.x;
  const int lane = tid & 63;
  const int wave = tid >> 6;
  const int row0 = blockIdx.x * BM;

  float4* xs4 = (float4*)smem;                     // prologue view

  // ---- stage x tile (coalesced float4), swizzle float4-col ^= (row>>2)&7 ----
  const float4* xg = (const float4*)(x + (size_t)row0 * D_DIM);
#pragma unroll
  for (int i = 0; i < 4; ++i) {
    int f = tid + i * NTHREADS;                    // 2048 float4
    int row = f >> 4, c4 = f & 15;
    xs4[row * 16 + (c4 ^ ((row >> 2) & 7))] = xg[f];
  }
  if (tid == 0) ovf_cnt = 0;
  if (tid < BM) cnt_s[tid] = 0;
  __syncthreads();

  // ---- xsq per row: numpy NPY_SIMD-128 pairwise emulation (verified R5) ----
  if (tid < BM) {
    const int swz = 4 * ((tid >> 2) & 7);
    const float* xr = (const float*)xs4 + tid * 64;
    float s[4];
#pragma unroll
    for (int l = 0; l < 4; ++l) {
      float rj[8];
#pragma unroll
      for (int j = 0; j < 8; ++j) {
        float a = xr[(4 * j + l) ^ swz];
        float b = xr[(32 + 4 * j + l) ^ swz];
        float ta = a * a;
        float tb = b * b;
        rj[j] = ta + tb;
      }
      s[l] = ((rj[0] + rj[1]) + (rj[2] + rj[3])) +
             ((rj[4] + rj[5]) + (rj[6] + rj[7]));
    }
    xsq_s[tid] = (s[0] + s[1]) + (s[2] + s[3]);
  }

  // ---- A fragments: wave owns rows wave*16..wave*16+15 (m89-verified maps:
  //   A: lane row=lane&15, k=(lane>>4)*8+j; B: col=lane&15, same k;
  //   C: col=lane&15, row=(lane>>4)*4+r)
  s16x8 a0, a1;
  {
    const int arow = lane & 15;
    const int kgA = (lane >> 4) * 8;
    const int row = wave * 16 + arow;
    const int sw = (row >> 2) & 7;
    {
      int q0 = kgA >> 2;
      float4 f0 = xs4[row * 16 + (q0 ^ sw)];
      float4 f1 = xs4[row * 16 + ((q0 + 1) ^ sw)];
      a0[0] = f2bf(f0.x); a0[1] = f2bf(f0.y); a0[2] = f2bf(f0.z); a0[3] = f2bf(f0.w);
      a0[4] = f2bf(f1.x); a0[5] = f2bf(f1.y); a0[6] = f2bf(f1.z); a0[7] = f2bf(f1.w);
    }
    {
      int q0 = (32 + kgA) >> 2;
      float4 f0 = xs4[row * 16 + (q0 ^ sw)];
      float4 f1 = xs4[row * 16 + ((q0 + 1) ^ sw)];
      a1[0] = f2bf(f0.x); a1[1] = f2bf(f0.y); a1[2] = f2bf(f0.z); a1[3] = f2bf(f0.w);
      a1[4] = f2bf(f1.x); a1[5] = f2bf(f1.y); a1[6] = f2bf(f1.z); a1[7] = f2bf(f1.w);
    }
  }
  __syncthreads();   // x tile dead; smem becomes bbuf[2][32KB]

  const int ccol = lane & 15;
  const int kg   = (lane >> 4) * 8;
  const int swb  = (ccol & 7) << 3;                // lane-constant
  const int rowbase = wave * 16 + (lane >> 4) * 4;

  // stage tile t (32 KB) into buffer b: 512 threads x 4 x 16B
  auto STAGE = [&](int t, int b) {
    const char* s0 = (const char*)cbh + (size_t)t * 32768 + wave * 4096 + lane * 16;
    char* d0 = smem + b * 32768 + wave * 4096;
    gload_lds16(s0, d0);
    gload_lds16(s0 + 1024, d0 + 1024);
    gload_lds16(s0 + 2048, d0 + 2048);
    gload_lds16(s0 + 3072, d0 + 3072);
  };

  // ================= pass 1: per-row screen min =================
  float minv[4];
  minv[0] = minv[1] = minv[2] = minv[3] = FLT_MAX;

  STAGE(0, 0);
  __syncthreads();
  for (int t = 0; t < NT; ++t) {
    if (t + 1 < NT) STAGE(t + 1, (t + 1) & 1);
    const unsigned short* B = (const unsigned short*)(smem + (t & 1) * 32768);
#pragma unroll
    for (int st = 0; st < 16; ++st) {
      const unsigned short* bp = B + (st * 16 + ccol) * 64;
      s16x8 b0 = *(const s16x8*)(bp + (kg ^ swb));
      s16x8 b1 = *(const s16x8*)(bp + ((32 + kg) ^ swb));
      f32x4 acc = {0.f, 0.f, 0.f, 0.f};
      acc = __builtin_amdgcn_mfma_f32_16x16x32_bf16(a0, b0, acc, 0, 0, 0);
      acc = __builtin_amdgcn_mfma_f32_16x16x32_bf16(a1, b1, acc, 0, 0, 0);
#pragma unroll
      for (int r = 0; r < 4; ++r) minv[r] = fminf(minv[r], acc[r]);
    }
    __syncthreads();
  }

  // per-row min across the 16 covering lanes (rows are wave-private)
#pragma unroll
  for (int r = 0; r < 4; ++r) {
    float v = minv[r];
#pragma unroll
    for (int m = 1; m <= 8; m <<= 1) v = fminf(v, __shfl_xor(v, m));
    minv[r] = v;
  }
  if ((lane & 15) == 0) {
#pragma unroll
    for (int r = 0; r < 4; ++r)
      rowthr_s[rowbase + r] = minv[r] + MARGIN;
  }
  __syncthreads();

  float thr[4];
#pragma unroll
  for (int r = 0; r < 4; ++r)
    thr[r] = rowthr_s[rowbase + r];

  // ====== pass 2: recompute (bit-identical), collect candidates ======
  STAGE(0, 0);
  __syncthreads();
  for (int t = 0; t < NT; ++t) {
    if (t + 1 < NT) STAGE(t + 1, (t + 1) & 1);
    const unsigned short* B = (const unsigned short*)(smem + (t & 1) * 32768);
#pragma unroll
    for (int st = 0; st < 16; ++st) {
      const unsigned short* bp = B + (st * 16 + ccol) * 64;
      s16x8 b0 = *(const s16x8*)(bp + (kg ^ swb));
      s16x8 b1 = *(const s16x8*)(bp + ((32 + kg) ^ swb));
      f32x4 acc = {0.f, 0.f, 0.f, 0.f};
      acc = __builtin_amdgcn_mfma_f32_16x16x32_bf16(a0, b0, acc, 0, 0, 0);
      acc = __builtin_amdgcn_mfma_f32_16x16x32_bf16(a1, b1, acc, 0, 0, 0);
#pragma unroll
      for (int r = 0; r < 4; ++r) {
        if (acc[r] <= thr[r]) {
          int row = rowbase + r;
          int pos = atomicAdd(&cnt_s[row], 1);
          if (pos < CAND_CAP) cand_s[row * CAND_CAP + pos] = t * KT + st * 16 + ccol;
        }
      }
    }
    __syncthreads();
  }

  // ====== exact rescore (R-scheme), lex-(dist,k); 4 threads per row.
  //        x read from GLOBAL (linear d-order: verified-passing order). ======
  {
    const int row = tid >> 2, slot = tid & 3;
    const int cnt = cnt_s[row];
    if (cnt <= CAND_CAP) {
      const float* xr = x + (size_t)(row0 + row) * D_DIM;
      const float xq = xsq_s[row];
      float bv = FLT_MAX; int bk = INT_MAX;
      for (int i = slot; i < cnt; i += 4) {
        int k = cand_s[row * CAND_CAP + i];
        const float* er = cb + (size_t)k * D_DIM;
        float a = 0.f;
#pragma unroll 8
        for (int d = 0; d < D_DIM; ++d) a = fmaf(xr[d], er[d], a);
        float dist = (xq + esq[k]) - 2.0f * a;
        if (dist < bv || (dist == bv && k < bk)) { bv = dist; bk = k; }
      }
#pragma unroll
      for (int m = 1; m <= 2; m <<= 1) {
        float ov = __shfl_xor(bv, m); int ok = __shfl_xor(bk, m);
        if (ov < bv || (ov == bv && ok < bk)) { bv = ov; bk = ok; }
      }
      if (slot == 0) bestk_s[row] = bk;
    }
  }
  if (tid < BM && cnt_s[tid] > CAND_CAP) {
    int p = atomicAdd(&ovf_cnt, 1);
    ovf_rows[p] = tid;
  }
  __syncthreads();

  // ====== lossless overflow fallback: block-cooperative full scan ======
  {
    const int novf = ovf_cnt;
    for (int i = 0; i < novf; ++i) {
      const int row = ovf_rows[i];
      const float* xr = x + (size_t)(row0 + row) * D_DIM;
      const float xq = xsq_s[row];
      float bv = FLT_MAX; int bk = INT_MAX;
      for (int k = tid; k < K_CB; k += NTHREADS) {
        const float* er = cb + (size_t)k * D_DIM;
        float a = 0.f;
#pragma unroll 8
        for (int d = 0; d < D_DIM; ++d) a = fmaf(xr[d], er[d], a);
        float dist = (xq + esq[k]) - 2.0f * a;
        if (dist < bv || (dist == bv && k < bk)) { bv = dist; bk = k; }
      }
#pragma unroll
      for (int m = 1; m <= 32; m <<= 1) {
        float ov = __shfl_xor(bv, m); int ok = __shfl_xor(bk, m);
        if (ov < bv || (ov == bv && ok < bk)) { bv = ov; bk = ok; }
      }
      if (lane == 0) { fb_v[wave] = bv; fb_k[wave] = bk; }
      __syncthreads();
      if (tid == 0) {
        float BV = fb_v[0]; int BK = fb_k[0];
#pragma unroll
        for (int w = 1; w < NWAVES; ++w)
          if (fb_v[w] < BV || (fb_v[w] == BV && fb_k[w] < BK)) { BV = fb_v[w]; BK = fb_k[w]; }
        bestk_s[row] = BK;
      }
      __syncthreads();
    }
  }
  __syncthreads();

  // ---- gather: out[row] = codebook[bestk[row]], coalesced float4 ----
  const float4* cb4 = (const float4*)cb;
  float4* out4 = (float4*)out + (size_t)row0 * 16;
#pragma unroll
  for (int i = 0; i < 4; ++i) {
    int f = tid + i * NTHREADS;
    int row = f >> 4, c4 = f & 15;
    out4[f] = cb4[(size_t)bestk_s[row] * 16 + c4];
  }
}

extern "C" void kernel_launch(void* const* d_in, const int* in_sizes, int n_in,
                              void* d_out, int out_size, void* d_ws, size_t ws_size,
                              hipStream_t stream) {
  const float* x  = (const float*)d_in[0];   // [N, 64] fp32
  const float* cb = (const float*)d_in[1];   // [2048, 64] fp32
  float* out = (float*)d_out;                // [N, 64] fp32
  float* esq = (float*)d_ws;                 // [2048] fp32
  unsigned short* cbh = (unsigned short*)d_ws + 4096;  // swizzled bf16(-2e), 256 KB

  const int N = in_sizes[0] / D_DIM;         // 131072

  prep_kernel<<<(K_CB + 255) / 256, 256, 0, stream>>>(cb, esq, cbh);
  vq_mfma_kernel<<<N / BM, NTHREADS, 0, stream>>>(x, cb, esq, cbh, out);
}

// Round 27
// 180.870 us; speedup vs baseline: 7.8112x; 1.3484x over previous
//
#include <hip/hip_runtime.h>
#include <float.h>
#include <limits.h>

// N=131072, K=2048, D=64.
// Verified reference scheme R (rounds 5/7/9-23, absmax 0.0):
//   xsq: numpy NPY_SIMD-128 pairwise (8 vec-accs x 4 lanes + SSE3 hadd tree)
//   esq: scalar pairwise-8; dot: any fp32 order (proven);
//   dist=fl(fl(xsq+esq)-2dot); argmin first-index.
// Round 27 = R23 byte-for-byte (verified best, 181.5us). R26's CAP 24->20
// shave regressed 34% (uniform dilation; either marginal overflow-fallback
// population or node variance) -- reverted. CAP 24 is the sweet spot:
// P(overflow)~1e-8/row AND LDS 80896 < 81920 keeps 2 blocks/CU (verified).
// Session ladder: 556 (exact fp32 VALU) -> 228 (MFMA screen + exact rescore)
// -> 202 (folded -2e epilogue) -> 193 (KT=128) -> 181.5 (KT=256). 3.07x,
// bit-exact argmin throughout (absmax 0.0 on every passing round).
#define D_DIM 64
#define K_CB  2048
#define BM    128
#define NTHREADS 512
#define NWAVES 8
#define KT    256               // codes per staged tile (32 KB)
#define NT    (K_CB / KT)       // 8 tiles
#define MARGIN 2e-3f
#define CAND_CAP 24

typedef __attribute__((ext_vector_type(4))) float f32x4;
typedef __attribute__((ext_vector_type(8))) short s16x8;

__device__ __forceinline__ short f2bf(float f) {   // RN-even fp32->bf16 bits
  unsigned u = __builtin_bit_cast(unsigned, f);
  u += 0x7fffu + ((u >> 16) & 1u);
  return (short)(unsigned short)(u >> 16);
}

__device__ __forceinline__ void gload_lds16(const void* g, void* l) {
  __builtin_amdgcn_global_load_lds(
      (const __attribute__((address_space(1))) unsigned int*)g,
      (__attribute__((address_space(3))) unsigned int*)l, 16, 0, 0);
}

// prep: esq[k] (scalar-8 numpy order, verified) + bf16(-2*e) PRE-SWIZZLED:
//   cbh[k*64 + (d ^ ((k&7)<<3))] = bf16(-2*cb[k][d])
__global__ void __launch_bounds__(256) prep_kernel(const float* __restrict__ cb,
                                                   float* __restrict__ esq,
                                                   unsigned short* __restrict__ cbh) {
#pragma clang fp contract(off)
  int k = blockIdx.x * 256 + threadIdx.x;
  if (k >= K_CB) return;
  const float* row = cb + (size_t)k * D_DIM;
  float r[8];
#pragma unroll
  for (int j = 0; j < 8; ++j) { float v = row[j]; r[j] = v * v; }
#pragma unroll
  for (int i = 1; i < 8; ++i)
#pragma unroll
    for (int j = 0; j < 8; ++j) { float v = row[8 * i + j]; r[j] += v * v; }
  esq[k] = ((r[0] + r[1]) + (r[2] + r[3])) + ((r[4] + r[5]) + (r[6] + r[7]));
  unsigned short* o = cbh + (size_t)k * D_DIM;
  const int sw = (k & 7) << 3;
#pragma unroll
  for (int d = 0; d < D_DIM; ++d)
    o[d ^ sw] = (unsigned short)f2bf(-2.0f * row[d]);
}

__global__ void __launch_bounds__(NTHREADS)
vq_mfma_kernel(const float* __restrict__ x,
               const float* __restrict__ cb,
               const float* __restrict__ esq,
               const unsigned short* __restrict__ cbh,
               float* __restrict__ out) {
#pragma clang fp contract(off)
  // 64 KB region: prologue = fp32 x tile (32 KB, first half);
  // steady = bbuf[2] (2 x 32 KB double-buffer).
  __shared__ __align__(16) char smem[65536];
  __shared__ int   cand_s[BM * CAND_CAP];          // 12 KB
  __shared__ float xsq_s[BM];
  __shared__ float rowthr_s[BM];
  __shared__ int   cnt_s[BM];
  __shared__ int   bestk_s[BM];
  __shared__ int   ovf_rows[BM];
  __shared__ int   ovf_cnt;
  __shared__ float fb_v[NWAVES];
  __shared__ int   fb_k[NWAVES];

  const int tid  = threadIdx.x;
  const int lane = tid & 63;
  const int wave = tid >> 6;
  const int row0 = blockIdx.x * BM;

  float4* xs4 = (float4*)smem;                     // prologue view

  // ---- stage x tile (coalesced float4), swizzle float4-col ^= (row>>2)&7 ----
  const float4* xg = (const float4*)(x + (size_t)row0 * D_DIM);
#pragma unroll
  for (int i = 0; i < 4; ++i) {
    int f = tid + i * NTHREADS;                    // 2048 float4
    int row = f >> 4, c4 = f & 15;
    xs4[row * 16 + (c4 ^ ((row >> 2) & 7))] = xg[f];
  }
  if (tid == 0) ovf_cnt = 0;
  if (tid < BM) cnt_s[tid] = 0;
  __syncthreads();

  // ---- xsq per row: numpy NPY_SIMD-128 pairwise emulation (verified R5) ----
  if (tid < BM) {
    const int swz = 4 * ((tid >> 2) & 7);
    const float* xr = (const float*)xs4 + tid * 64;
    float s[4];
#pragma unroll
    for (int l = 0; l < 4; ++l) {
      float rj[8];
#pragma unroll
      for (int j = 0; j < 8; ++j) {
        float a = xr[(4 * j + l) ^ swz];
        float b = xr[(32 + 4 * j + l) ^ swz];
        float ta = a * a;
        float tb = b * b;
        rj[j] = ta + tb;
      }
      s[l] = ((rj[0] + rj[1]) + (rj[2] + rj[3])) +
             ((rj[4] + rj[5]) + (rj[6] + rj[7]));
    }
    xsq_s[tid] = (s[0] + s[1]) + (s[2] + s[3]);
  }

  // ---- A fragments: wave owns rows wave*16..wave*16+15 (m89-verified maps:
  //   A: lane row=lane&15, k=(lane>>4)*8+j; B: col=lane&15, same k;
  //   C: col=lane&15, row=(lane>>4)*4+r)
  s16x8 a0, a1;
  {
    const int arow = lane & 15;
    const int kgA = (lane >> 4) * 8;
    const int row = wave * 16 + arow;
    const int sw = (row >> 2) & 7;
    {
      int q0 = kgA >> 2;
      float4 f0 = xs4[row * 16 + (q0 ^ sw)];
      float4 f1 = xs4[row * 16 + ((q0 + 1) ^ sw)];
      a0[0] = f2bf(f0.x); a0[1] = f2bf(f0.y); a0[2] = f2bf(f0.z); a0[3] = f2bf(f0.w);
      a0[4] = f2bf(f1.x); a0[5] = f2bf(f1.y); a0[6] = f2bf(f1.z); a0[7] = f2bf(f1.w);
    }
    {
      int q0 = (32 + kgA) >> 2;
      float4 f0 = xs4[row * 16 + (q0 ^ sw)];
      float4 f1 = xs4[row * 16 + ((q0 + 1) ^ sw)];
      a1[0] = f2bf(f0.x); a1[1] = f2bf(f0.y); a1[2] = f2bf(f0.z); a1[3] = f2bf(f0.w);
      a1[4] = f2bf(f1.x); a1[5] = f2bf(f1.y); a1[6] = f2bf(f1.z); a1[7] = f2bf(f1.w);
    }
  }
  __syncthreads();   // x tile dead; smem becomes bbuf[2][32KB]

  const int ccol = lane & 15;
  const int kg   = (lane >> 4) * 8;
  const int swb  = (ccol & 7) << 3;                // lane-constant
  const int rowbase = wave * 16 + (lane >> 4) * 4;

  // stage tile t (32 KB) into buffer b: 512 threads x 4 x 16B
  auto STAGE = [&](int t, int b) {
    const char* s0 = (const char*)cbh + (size_t)t * 32768 + wave * 4096 + lane * 16;
    char* d0 = smem + b * 32768 + wave * 4096;
    gload_lds16(s0, d0);
    gload_lds16(s0 + 1024, d0 + 1024);
    gload_lds16(s0 + 2048, d0 + 2048);
    gload_lds16(s0 + 3072, d0 + 3072);
  };

  // ================= pass 1: per-row screen min =================
  float minv[4];
  minv[0] = minv[1] = minv[2] = minv[3] = FLT_MAX;

  STAGE(0, 0);
  __syncthreads();
  for (int t = 0; t < NT; ++t) {
    if (t + 1 < NT) STAGE(t + 1, (t + 1) & 1);
    const unsigned short* B = (const unsigned short*)(smem + (t & 1) * 32768);
#pragma unroll
    for (int st = 0; st < 16; ++st) {
      const unsigned short* bp = B + (st * 16 + ccol) * 64;
      s16x8 b0 = *(const s16x8*)(bp + (kg ^ swb));
      s16x8 b1 = *(const s16x8*)(bp + ((32 + kg) ^ swb));
      f32x4 acc = {0.f, 0.f, 0.f, 0.f};
      acc = __builtin_amdgcn_mfma_f32_16x16x32_bf16(a0, b0, acc, 0, 0, 0);
      acc = __builtin_amdgcn_mfma_f32_16x16x32_bf16(a1, b1, acc, 0, 0, 0);
#pragma unroll
      for (int r = 0; r < 4; ++r) minv[r] = fminf(minv[r], acc[r]);
    }
    __syncthreads();
  }

  // per-row min across the 16 covering lanes (rows are wave-private)
#pragma unroll
  for (int r = 0; r < 4; ++r) {
    float v = minv[r];
#pragma unroll
    for (int m = 1; m <= 8; m <<= 1) v = fminf(v, __shfl_xor(v, m));
    minv[r] = v;
  }
  if ((lane & 15) == 0) {
#pragma unroll
    for (int r = 0; r < 4; ++r)
      rowthr_s[rowbase + r] = minv[r] + MARGIN;
  }
  __syncthreads();

  float thr[4];
#pragma unroll
  for (int r = 0; r < 4; ++r)
    thr[r] = rowthr_s[rowbase + r];

  // ====== pass 2: recompute (bit-identical), collect candidates ======
  STAGE(0, 0);
  __syncthreads();
  for (int t = 0; t < NT; ++t) {
    if (t + 1 < NT) STAGE(t + 1, (t + 1) & 1);
    const unsigned short* B = (const unsigned short*)(smem + (t & 1) * 32768);
#pragma unroll
    for (int st = 0; st < 16; ++st) {
      const unsigned short* bp = B + (st * 16 + ccol) * 64;
      s16x8 b0 = *(const s16x8*)(bp + (kg ^ swb));
      s16x8 b1 = *(const s16x8*)(bp + ((32 + kg) ^ swb));
      f32x4 acc = {0.f, 0.f, 0.f, 0.f};
      acc = __builtin_amdgcn_mfma_f32_16x16x32_bf16(a0, b0, acc, 0, 0, 0);
      acc = __builtin_amdgcn_mfma_f32_16x16x32_bf16(a1, b1, acc, 0, 0, 0);
#pragma unroll
      for (int r = 0; r < 4; ++r) {
        if (acc[r] <= thr[r]) {
          int row = rowbase + r;
          int pos = atomicAdd(&cnt_s[row], 1);
          if (pos < CAND_CAP) cand_s[row * CAND_CAP + pos] = t * KT + st * 16 + ccol;
        }
      }
    }
    __syncthreads();
  }

  // ====== exact rescore (R-scheme), lex-(dist,k); 4 threads per row.
  //        x read from GLOBAL (linear d-order: verified-passing order). ======
  {
    const int row = tid >> 2, slot = tid & 3;
    const int cnt = cnt_s[row];
    if (cnt <= CAND_CAP) {
      const float* xr = x + (size_t)(row0 + row) * D_DIM;
      const float xq = xsq_s[row];
      float bv = FLT_MAX; int bk = INT_MAX;
      for (int i = slot; i < cnt; i += 4) {
        int k = cand_s[row * CAND_CAP + i];
        const float* er = cb + (size_t)k * D_DIM;
        float a = 0.f;
#pragma unroll 8
        for (int d = 0; d < D_DIM; ++d) a = fmaf(xr[d], er[d], a);
        float dist = (xq + esq[k]) - 2.0f * a;
        if (dist < bv || (dist == bv && k < bk)) { bv = dist; bk = k; }
      }
#pragma unroll
      for (int m = 1; m <= 2; m <<= 1) {
        float ov = __shfl_xor(bv, m); int ok = __shfl_xor(bk, m);
        if (ov < bv || (ov == bv && ok < bk)) { bv = ov; bk = ok; }
      }
      if (slot == 0) bestk_s[row] = bk;
    }
  }
  if (tid < BM && cnt_s[tid] > CAND_CAP) {
    int p = atomicAdd(&ovf_cnt, 1);
    ovf_rows[p] = tid;
  }
  __syncthreads();

  // ====== lossless overflow fallback: block-cooperative full scan ======
  {
    const int novf = ovf_cnt;
    for (int i = 0; i < novf; ++i) {
      const int row = ovf_rows[i];
      const float* xr = x + (size_t)(row0 + row) * D_DIM;
      const float xq = xsq_s[row];
      float bv = FLT_MAX; int bk = INT_MAX;
      for (int k = tid; k < K_CB; k += NTHREADS) {
        const float* er = cb + (size_t)k * D_DIM;
        float a = 0.f;
#pragma unroll 8
        for (int d = 0; d < D_DIM; ++d) a = fmaf(xr[d], er[d], a);
        float dist = (xq + esq[k]) - 2.0f * a;
        if (dist < bv || (dist == bv && k < bk)) { bv = dist; bk = k; }
      }
#pragma unroll
      for (int m = 1; m <= 32; m <<= 1) {
        float ov = __shfl_xor(bv, m); int ok = __shfl_xor(bk, m);
        if (ov < bv || (ov == bv && ok < bk)) { bv = ov; bk = ok; }
      }
      if (lane == 0) { fb_v[wave] = bv; fb_k[wave] = bk; }
      __syncthreads();
      if (tid == 0) {
        float BV = fb_v[0]; int BK = fb_k[0];
#pragma unroll
        for (int w = 1; w < NWAVES; ++w)
          if (fb_v[w] < BV || (fb_v[w] == BV && fb_k[w] < BK)) { BV = fb_v[w]; BK = fb_k[w]; }
        bestk_s[row] = BK;
      }
      __syncthreads();
    }
  }
  __syncthreads();

  // ---- gather: out[row] = codebook[bestk[row]], coalesced float4 ----
  const float4* cb4 = (const float4*)cb;
  float4* out4 = (float4*)out + (size_t)row0 * 16;
#pragma unroll
  for (int i = 0; i < 4; ++i) {
    int f = tid + i * NTHREADS;
    int row = f >> 4, c4 = f & 15;
    out4[f] = cb4[(size_t)bestk_s[row] * 16 + c4];
  }
}

extern "C" void kernel_launch(void* const* d_in, const int* in_sizes, int n_in,
                              void* d_out, int out_size, void* d_ws, size_t ws_size,
                              hipStream_t stream) {
  const float* x  = (const float*)d_in[0];   // [N, 64] fp32
  const float* cb = (const float*)d_in[1];   // [2048, 64] fp32
  float* out = (float*)d_out;                // [N, 64] fp32
  float* esq = (float*)d_ws;                 // [2048] fp32
  unsigned short* cbh = (unsigned short*)d_ws + 4096;  // swizzled bf16(-2e), 256 KB

  const int N = in_sizes[0] / D_DIM;         // 131072

  prep_kernel<<<(K_CB + 255) / 256, 256, 0, stream>>>(cb, esq, cbh);
  vq_mfma_kernel<<<N / BM, NTHREADS, 0, stream>>>(x, cb, esq, cbh, out);
}

// Round 28
// 178.325 us; speedup vs baseline: 7.9226x; 1.0143x over previous
//
#include <hip/hip_runtime.h>
#include <float.h>
#include <limits.h>

// N=131072, K=2048, D=64.
// Verified reference scheme R (rounds 5/7/9-23/27, absmax 0.0):
//   xsq: numpy NPY_SIMD-128 pairwise (8 vec-accs x 4 lanes + SSE3 hadd tree)
//   esq: scalar pairwise-8; dot: any fp32 order (proven);
//   dist=fl(fl(xsq+esq)-2dot); argmin first-index.
// Round 28: halve the 8x LDS-read redundancy (the wall's largest resource:
// ~82us of ds_read-pipe occupancy in a 181us kernel) WITHOUT the LDS-capacity
// bump that killed R24. Waves split (rw=wave&3, cg=wave>>2): each owns 32
// rows (2 row-tiles) x half of each staged tile (8 subtiles). One b0/b1 LDS
// read pair now feeds 4 MFMAs (was 2) -> ds_read/pass halves; MFMA count,
// staging, candidate semantics unchanged. Row-min combined across the 2
// code-halves via rowmin_s[2][BM] (replaces rowthr_s; ovf_rows->ushort) ->
// LDS ~80.7KB, still 2 blocks/CU. Everything else = R23/R27 (180.9us).
#define D_DIM 64
#define K_CB  2048
#define BM    128
#define NTHREADS 512
#define NWAVES 8
#define KT    256               // codes per staged tile (32 KB)
#define NT    (K_CB / KT)       // 8 tiles
#define MARGIN 2e-3f
#define CAND_CAP 24

typedef __attribute__((ext_vector_type(4))) float f32x4;
typedef __attribute__((ext_vector_type(8))) short s16x8;

__device__ __forceinline__ short f2bf(float f) {   // RN-even fp32->bf16 bits
  unsigned u = __builtin_bit_cast(unsigned, f);
  u += 0x7fffu + ((u >> 16) & 1u);
  return (short)(unsigned short)(u >> 16);
}

__device__ __forceinline__ void gload_lds16(const void* g, void* l) {
  __builtin_amdgcn_global_load_lds(
      (const __attribute__((address_space(1))) unsigned int*)g,
      (__attribute__((address_space(3))) unsigned int*)l, 16, 0, 0);
}

// prep: esq[k] (scalar-8 numpy order, verified) + bf16(-2*e) PRE-SWIZZLED:
//   cbh[k*64 + (d ^ ((k&7)<<3))] = bf16(-2*cb[k][d])
__global__ void __launch_bounds__(256) prep_kernel(const float* __restrict__ cb,
                                                   float* __restrict__ esq,
                                                   unsigned short* __restrict__ cbh) {
#pragma clang fp contract(off)
  int k = blockIdx.x * 256 + threadIdx.x;
  if (k >= K_CB) return;
  const float* row = cb + (size_t)k * D_DIM;
  float r[8];
#pragma unroll
  for (int j = 0; j < 8; ++j) { float v = row[j]; r[j] = v * v; }
#pragma unroll
  for (int i = 1; i < 8; ++i)
#pragma unroll
    for (int j = 0; j < 8; ++j) { float v = row[8 * i + j]; r[j] += v * v; }
  esq[k] = ((r[0] + r[1]) + (r[2] + r[3])) + ((r[4] + r[5]) + (r[6] + r[7]));
  unsigned short* o = cbh + (size_t)k * D_DIM;
  const int sw = (k & 7) << 3;
#pragma unroll
  for (int d = 0; d < D_DIM; ++d)
    o[d ^ sw] = (unsigned short)f2bf(-2.0f * row[d]);
}

__global__ void __launch_bounds__(NTHREADS)
vq_mfma_kernel(const float* __restrict__ x,
               const float* __restrict__ cb,
               const float* __restrict__ esq,
               const unsigned short* __restrict__ cbh,
               float* __restrict__ out) {
#pragma clang fp contract(off)
  // 64 KB region: prologue = fp32 x tile (32 KB, first half);
  // steady = bbuf[2] (2 x 32 KB double-buffer).
  __shared__ __align__(16) char smem[65536];
  __shared__ int   cand_s[BM * CAND_CAP];          // 12 KB
  __shared__ float xsq_s[BM];
  __shared__ float rowmin_s[2][BM];                // per code-half partial min
  __shared__ int   cnt_s[BM];
  __shared__ int   bestk_s[BM];
  __shared__ unsigned short ovf_rows[BM];
  __shared__ int   ovf_cnt;
  __shared__ float fb_v[NWAVES];
  __shared__ int   fb_k[NWAVES];

  const int tid  = threadIdx.x;
  const int lane = tid & 63;
  const int wave = tid >> 6;
  const int rw   = wave & 3;               // row group (32 rows)
  const int cg   = wave >> 2;              // code half (8 of 16 subtiles)
  const int row0 = blockIdx.x * BM;

  float4* xs4 = (float4*)smem;                     // prologue view

  // ---- stage x tile (coalesced float4), swizzle float4-col ^= (row>>2)&7 ----
  const float4* xg = (const float4*)(x + (size_t)row0 * D_DIM);
#pragma unroll
  for (int i = 0; i < 4; ++i) {
    int f = tid + i * NTHREADS;                    // 2048 float4
    int row = f >> 4, c4 = f & 15;
    xs4[row * 16 + (c4 ^ ((row >> 2) & 7))] = xg[f];
  }
  if (tid == 0) ovf_cnt = 0;
  if (tid < BM) cnt_s[tid] = 0;
  __syncthreads();

  // ---- xsq per row: numpy NPY_SIMD-128 pairwise emulation (verified R5) ----
  if (tid < BM) {
    const int swz = 4 * ((tid >> 2) & 7);
    const float* xr = (const float*)xs4 + tid * 64;
    float s[4];
#pragma unroll
    for (int l = 0; l < 4; ++l) {
      float rj[8];
#pragma unroll
      for (int j = 0; j < 8; ++j) {
        float a = xr[(4 * j + l) ^ swz];
        float b = xr[(32 + 4 * j + l) ^ swz];
        float ta = a * a;
        float tb = b * b;
        rj[j] = ta + tb;
      }
      s[l] = ((rj[0] + rj[1]) + (rj[2] + rj[3])) +
             ((rj[4] + rj[5]) + (rj[6] + rj[7]));
    }
    xsq_s[tid] = (s[0] + s[1]) + (s[2] + s[3]);
  }

  // ---- A fragments: wave owns rows rw*32 .. rw*32+31 (2 row-tiles).
  //   16x16x32 maps (m89-verified): A: lane row=lane&15, k=(lane>>4)*8+j;
  //   B: col=lane&15, same k; C: col=lane&15, row=(lane>>4)*4+r.
  s16x8 a0[2], a1[2];
  {
    const int arow = lane & 15;
    const int kgA = (lane >> 4) * 8;
#pragma unroll
    for (int rt = 0; rt < 2; ++rt) {
      int row = rw * 32 + rt * 16 + arow;
      int sw = (row >> 2) & 7;
      {
        int q0 = kgA >> 2;
        float4 f0 = xs4[row * 16 + (q0 ^ sw)];
        float4 f1 = xs4[row * 16 + ((q0 + 1) ^ sw)];
        a0[rt][0] = f2bf(f0.x); a0[rt][1] = f2bf(f0.y);
        a0[rt][2] = f2bf(f0.z); a0[rt][3] = f2bf(f0.w);
        a0[rt][4] = f2bf(f1.x); a0[rt][5] = f2bf(f1.y);
        a0[rt][6] = f2bf(f1.z); a0[rt][7] = f2bf(f1.w);
      }
      {
        int q0 = (32 + kgA) >> 2;
        float4 f0 = xs4[row * 16 + (q0 ^ sw)];
        float4 f1 = xs4[row * 16 + ((q0 + 1) ^ sw)];
        a1[rt][0] = f2bf(f0.x); a1[rt][1] = f2bf(f0.y);
        a1[rt][2] = f2bf(f0.z); a1[rt][3] = f2bf(f0.w);
        a1[rt][4] = f2bf(f1.x); a1[rt][5] = f2bf(f1.y);
        a1[rt][6] = f2bf(f1.z); a1[rt][7] = f2bf(f1.w);
      }
    }
  }
  __syncthreads();   // x tile dead; smem becomes bbuf[2][32KB]

  const int ccol = lane & 15;
  const int kg   = (lane >> 4) * 8;
  const int swb  = (ccol & 7) << 3;                // lane-constant
  const int rsub = (lane >> 4) * 4;                // row = rw*32 + rt*16 + rsub + r

  // stage tile t (32 KB) into buffer b: 512 threads x 4 x 16B
  auto STAGE = [&](int t, int b) {
    const char* s0 = (const char*)cbh + (size_t)t * 32768 + wave * 4096 + lane * 16;
    char* d0 = smem + b * 32768 + wave * 4096;
    gload_lds16(s0, d0);
    gload_lds16(s0 + 1024, d0 + 1024);
    gload_lds16(s0 + 2048, d0 + 2048);
    gload_lds16(s0 + 3072, d0 + 3072);
  };

  // ================= pass 1: per-row screen min =================
  float minv[2][4];
#pragma unroll
  for (int rt = 0; rt < 2; ++rt)
#pragma unroll
    for (int r = 0; r < 4; ++r) minv[rt][r] = FLT_MAX;

  STAGE(0, 0);
  __syncthreads();
  for (int t = 0; t < NT; ++t) {
    if (t + 1 < NT) STAGE(t + 1, (t + 1) & 1);
    const unsigned short* B = (const unsigned short*)(smem + (t & 1) * 32768);
#pragma unroll
    for (int st = 0; st < 8; ++st) {
      const int sti = cg * 8 + st;                 // this wave's code half
      const unsigned short* bp = B + (sti * 16 + ccol) * 64;
      s16x8 b0 = *(const s16x8*)(bp + (kg ^ swb));
      s16x8 b1 = *(const s16x8*)(bp + ((32 + kg) ^ swb));
#pragma unroll
      for (int rt = 0; rt < 2; ++rt) {
        f32x4 acc = {0.f, 0.f, 0.f, 0.f};
        acc = __builtin_amdgcn_mfma_f32_16x16x32_bf16(a0[rt], b0, acc, 0, 0, 0);
        acc = __builtin_amdgcn_mfma_f32_16x16x32_bf16(a1[rt], b1, acc, 0, 0, 0);
#pragma unroll
        for (int r = 0; r < 4; ++r) minv[rt][r] = fminf(minv[rt][r], acc[r]);
      }
    }
    __syncthreads();
  }

  // per-row min across the 16 covering lanes, per code half
#pragma unroll
  for (int rt = 0; rt < 2; ++rt)
#pragma unroll
    for (int r = 0; r < 4; ++r) {
      float v = minv[rt][r];
#pragma unroll
      for (int m = 1; m <= 8; m <<= 1) v = fminf(v, __shfl_xor(v, m));
      minv[rt][r] = v;
    }
  if ((lane & 15) == 0) {
#pragma unroll
    for (int rt = 0; rt < 2; ++rt)
#pragma unroll
      for (int r = 0; r < 4; ++r)
        rowmin_s[cg][rw * 32 + rt * 16 + rsub + r] = minv[rt][r];
  }
  __syncthreads();

  // thr = min over both code halves + MARGIN (computed per thread, no LDS buf)
  float thr[2][4];
#pragma unroll
  for (int rt = 0; rt < 2; ++rt)
#pragma unroll
    for (int r = 0; r < 4; ++r) {
      int row = rw * 32 + rt * 16 + rsub + r;
      thr[rt][r] = fminf(rowmin_s[0][row], rowmin_s[1][row]) + MARGIN;
    }

  // ====== pass 2: recompute (bit-identical), collect candidates ======
  STAGE(0, 0);
  __syncthreads();
  for (int t = 0; t < NT; ++t) {
    if (t + 1 < NT) STAGE(t + 1, (t + 1) & 1);
    const unsigned short* B = (const unsigned short*)(smem + (t & 1) * 32768);
#pragma unroll
    for (int st = 0; st < 8; ++st) {
      const int sti = cg * 8 + st;
      const unsigned short* bp = B + (sti * 16 + ccol) * 64;
      s16x8 b0 = *(const s16x8*)(bp + (kg ^ swb));
      s16x8 b1 = *(const s16x8*)(bp + ((32 + kg) ^ swb));
#pragma unroll
      for (int rt = 0; rt < 2; ++rt) {
        f32x4 acc = {0.f, 0.f, 0.f, 0.f};
        acc = __builtin_amdgcn_mfma_f32_16x16x32_bf16(a0[rt], b0, acc, 0, 0, 0);
        acc = __builtin_amdgcn_mfma_f32_16x16x32_bf16(a1[rt], b1, acc, 0, 0, 0);
#pragma unroll
        for (int r = 0; r < 4; ++r) {
          if (acc[r] <= thr[rt][r]) {
            int row = rw * 32 + rt * 16 + rsub + r;
            int pos = atomicAdd(&cnt_s[row], 1);
            if (pos < CAND_CAP)
              cand_s[row * CAND_CAP + pos] = t * KT + sti * 16 + ccol;
          }
        }
      }
    }
    __syncthreads();
  }

  // ====== exact rescore (R-scheme), lex-(dist,k); 4 threads per row.
  //        x read from GLOBAL (linear d-order: verified-passing order). ======
  {
    const int row = tid >> 2, slot = tid & 3;
    const int cnt = cnt_s[row];
    if (cnt <= CAND_CAP) {
      const float* xr = x + (size_t)(row0 + row) * D_DIM;
      const float xq = xsq_s[row];
      float bv = FLT_MAX; int bk = INT_MAX;
      for (int i = slot; i < cnt; i += 4) {
        int k = cand_s[row * CAND_CAP + i];
        const float* er = cb + (size_t)k * D_DIM;
        float a = 0.f;
#pragma unroll 8
        for (int d = 0; d < D_DIM; ++d) a = fmaf(xr[d], er[d], a);
        float dist = (xq + esq[k]) - 2.0f * a;
        if (dist < bv || (dist == bv && k < bk)) { bv = dist; bk = k; }
      }
#pragma unroll
      for (int m = 1; m <= 2; m <<= 1) {
        float ov = __shfl_xor(bv, m); int ok = __shfl_xor(bk, m);
        if (ov < bv || (ov == bv && ok < bk)) { bv = ov; bk = ok; }
      }
      if (slot == 0) bestk_s[row] = bk;
    }
  }
  if (tid < BM && cnt_s[tid] > CAND_CAP) {
    int p = atomicAdd(&ovf_cnt, 1);
    ovf_rows[p] = (unsigned short)tid;
  }
  __syncthreads();

  // ====== lossless overflow fallback: block-cooperative full scan ======
  {
    const int novf = ovf_cnt;
    for (int i = 0; i < novf; ++i) {
      const int row = ovf_rows[i];
      const float* xr = x + (size_t)(row0 + row) * D_DIM;
      const float xq = xsq_s[row];
      float bv = FLT_MAX; int bk = INT_MAX;
      for (int k = tid; k < K_CB; k += NTHREADS) {
        const float* er = cb + (size_t)k * D_DIM;
        float a = 0.f;
#pragma unroll 8
        for (int d = 0; d < D_DIM; ++d) a = fmaf(xr[d], er[d], a);
        float dist = (xq + esq[k]) - 2.0f * a;
        if (dist < bv || (dist == bv && k < bk)) { bv = dist; bk = k; }
      }
#pragma unroll
      for (int m = 1; m <= 32; m <<= 1) {
        float ov = __shfl_xor(bv, m); int ok = __shfl_xor(bk, m);
        if (ov < bv || (ov == bv && ok < bk)) { bv = ov; bk = ok; }
      }
      if (lane == 0) { fb_v[wave] = bv; fb_k[wave] = bk; }
      __syncthreads();
      if (tid == 0) {
        float BV = fb_v[0]; int BK = fb_k[0];
#pragma unroll
        for (int w = 1; w < NWAVES; ++w)
          if (fb_v[w] < BV || (fb_v[w] == BV && fb_k[w] < BK)) { BV = fb_v[w]; BK = fb_k[w]; }
        bestk_s[row] = BK;
      }
      __syncthreads();
    }
  }
  __syncthreads();

  // ---- gather: out[row] = codebook[bestk[row]], coalesced float4 ----
  const float4* cb4 = (const float4*)cb;
  float4* out4 = (float4*)out + (size_t)row0 * 16;
#pragma unroll
  for (int i = 0; i < 4; ++i) {
    int f = tid + i * NTHREADS;
    int row = f >> 4, c4 = f & 15;
    out4[f] = cb4[(size_t)bestk_s[row] * 16 + c4];
  }
}

extern "C" void kernel_launch(void* const* d_in, const int* in_sizes, int n_in,
                              void* d_out, int out_size, void* d_ws, size_t ws_size,
                              hipStream_t stream) {
  const float* x  = (const float*)d_in[0];   // [N, 64] fp32
  const float* cb = (const float*)d_in[1];   // [2048, 64] fp32
  float* out = (float*)d_out;                // [N, 64] fp32
  float* esq = (float*)d_ws;                 // [2048] fp32
  unsigned short* cbh = (unsigned short*)d_ws + 4096;  // swizzled bf16(-2e), 256 KB

  const int N = in_sizes[0] / D_DIM;         // 131072

  prep_kernel<<<(K_CB + 255) / 256, 256, 0, stream>>>(cb, esq, cbh);
  vq_mfma_kernel<<<N / BM, NTHREADS, 0, stream>>>(x, cb, esq, cbh, out);
}